// Round 18
// baseline (215.458 us; speedup 1.0000x reference)
//
#include <hip/hip_runtime.h>
#include <hip/hip_bf16.h>
#include <stdint.h>

#define N_NODES 100000
#define N_EDGES 320000
#define DIM 128
#define AGG_EPS 1e-6f
#define BN_EPS 1e-5f
#define NODE_BLOCKS 2048
#define SCAN_BLOCKS 391   // ceil(100000/256)
#define GEMM_BLOCKS 782   // ceil(100000/128)
#define EDGE_BLOCKS 1250  // ceil(320000/256)

typedef float f32x4 __attribute__((ext_vector_type(4)));
typedef float f32x2 __attribute__((ext_vector_type(2)));
typedef __bf16 bf16x8 __attribute__((ext_vector_type(8)));

__device__ __forceinline__ uint32_t f2bf(float f) {
  union { float f; uint32_t u; } v; v.f = f;
  uint32_t u = v.u;
  return (u + 0x7fffu + ((u >> 16) & 1u)) >> 16;  // RNE
}
__device__ __forceinline__ float bf2f(uint32_t h) {
  union { uint32_t u; float f; } v; v.u = h << 16;
  return v.f;
}
__device__ __forceinline__ void nt_store2(float* p, float a, float b) {
  f32x2 v = {a, b};
  __builtin_nontemporal_store(v, (f32x2*)p);
}

// abde row layout (1024 B per node):
//   [0,512):   interleaved Ex|Bx  (lane l uint2 -> ex pair, bx pair)
//   [512,1024): interleaved Ax|Dx

// ---------------- K0: W -> wt transposed bf16; bias; zero cnt + done ----------
__global__ __launch_bounds__(256) void k_prep(
    const float* __restrict__ Wa, const float* __restrict__ ba,
    const float* __restrict__ Wb, const float* __restrict__ bb,
    const float* __restrict__ Wd, const float* __restrict__ bd,
    const float* __restrict__ We, const float* __restrict__ be,
    ushort* __restrict__ wt, float* __restrict__ biasc,
    uint4* __restrict__ cnt_zero, int* __restrict__ done) {
  __shared__ float tile[64][65];
  const int tid = threadIdx.x;
  const int b = blockIdx.x;
  const int sel = b >> 2, tr = (b >> 1) & 1, tc = b & 1;
  const float* W = (sel == 0) ? Wa : (sel == 1) ? Wb : (sel == 2) ? Wd : We;
#pragma unroll
  for (int i = 0; i < 16; ++i) {
    int idx = tid + 256 * i;
    int lr = idx >> 6, lc = idx & 63;
    tile[lr][lc] = W[(tr * 64 + lr) * 128 + tc * 64 + lc];
  }
  __syncthreads();
#pragma unroll
  for (int i = 0; i < 16; ++i) {
    int idx = tid + 256 * i;
    int oc = idx >> 6, ok = idx & 63;
    wt[(sel * 128 + tc * 64 + oc) * 128 + tr * 64 + ok] = (ushort)f2bf(tile[ok][oc]);
  }
  if (b == 0) {
    for (int t = tid; t < 512; t += 256) {
      int s2 = t >> 7;
      const float* bp = (s2 == 0) ? ba : (s2 == 1) ? bb : (s2 == 2) ? bd : be;
      biasc[t] = bp[t & 127];
    }
    if (tid == 0) *done = 0;
  }
  for (int j = b * 256 + tid; j < 25000; j += 16 * 256)
    cnt_zero[j] = make_uint4(0u, 0u, 0u, 0u);
}

// ---------------- K1: mixed-role — blocks <GEMM_BLOCKS: ABDE gemm; rest: edge count ----
__global__ __launch_bounds__(256) void k_gemm_count(
    const float* __restrict__ x, const ushort* __restrict__ wt,
    const float* __restrict__ biasc, ushort* __restrict__ abde,
    const int* __restrict__ dst, int* __restrict__ cnt) {
  __shared__ ushort As[128 * 128];  // 32KB: A tile; reused as bounce buffer
  __shared__ ushort Bs[64 * 128];   // 16KB
  const int tid = threadIdx.x;
  const int bid = blockIdx.x;

  if (bid >= GEMM_BLOCKS) {  // ---- count role ----
    int e = (bid - GEMM_BLOCKS) * 256 + tid;
    if (e < N_EDGES) atomicAdd(&cnt[dst[e]], 1);
    return;
  }
  const int m0 = bid * 128;

#pragma unroll
  for (int i = 0; i < 8; ++i) {
    int qid = tid + 256 * i;
    int row = qid >> 4, q = qid & 15;
    int gr = m0 + row;
    uint4 pk = make_uint4(0u, 0u, 0u, 0u);
    if (gr < N_NODES) {
      const float* s = x + (size_t)gr * 128 + q * 8;
      float4 f0 = *(const float4*)(s);
      float4 f1 = *(const float4*)(s + 4);
      pk.x = f2bf(f0.x) | (f2bf(f0.y) << 16);
      pk.y = f2bf(f0.z) | (f2bf(f0.w) << 16);
      pk.z = f2bf(f1.x) | (f2bf(f1.y) << 16);
      pk.w = f2bf(f1.z) | (f2bf(f1.w) << 16);
    }
    int byte = (row * 256 + q * 16) ^ ((row & 7) << 4);
    *(uint4*)((char*)As + byte) = pk;
  }
  __syncthreads();

  const int w = tid >> 6, lane = tid & 63;
  const int r = lane & 15, g = lane >> 4;

  bf16x8 afrag[2][4];
#pragma unroll
  for (int m = 0; m < 2; ++m)
#pragma unroll
    for (int kk = 0; kk < 4; ++kk) {
      int arow = w * 32 + m * 16 + r;
      int ab = (arow * 256 + kk * 64 + g * 16) ^ ((arow & 7) << 4);
      afrag[m][kk] = *(const bf16x8*)((const char*)As + ab);
    }

  const int ntpair[4][2] = {{2, 6}, {3, 7}, {0, 4}, {1, 5}};
  for (int ph = 0; ph < 4; ++ph) {
    f32x4 acc[2][2][4] = {};  // [t2][m][n]
#pragma unroll
    for (int t2 = 0; t2 < 2; ++t2) {
      if (ph | t2) __syncthreads();
      const int n0 = ntpair[ph][t2] * 64;
#pragma unroll
      for (int i = 0; i < 4; ++i) {
        int qid = tid + 256 * i;
        int row = qid >> 4, q = qid & 15;
        uint4 v = *(const uint4*)(wt + (n0 + row) * 128 + q * 8);
        int byte = (row * 256 + q * 16) ^ ((row & 7) << 4);
        *(uint4*)((char*)Bs + byte) = v;
      }
      __syncthreads();
#pragma unroll
      for (int kk = 0; kk < 4; ++kk) {
        bf16x8 bv[4];
#pragma unroll
        for (int n = 0; n < 4; ++n) {
          int brow = n * 16 + r;
          int bb = (brow * 256 + kk * 64 + g * 16) ^ ((brow & 7) << 4);
          bv[n] = *(const bf16x8*)((const char*)Bs + bb);
        }
#pragma unroll
        for (int m = 0; m < 2; ++m)
#pragma unroll
          for (int n = 0; n < 4; ++n)
            acc[t2][m][n] = __builtin_amdgcn_mfma_f32_16x16x32_bf16(
                afrag[m][kk], bv[n], acc[t2][m][n], 0, 0, 0);
      }
    }
#pragma unroll
    for (int t2 = 0; t2 < 2; ++t2) {
#pragma unroll
      for (int m = 0; m < 2; ++m) {
#pragma unroll
        for (int n = 0; n < 4; ++n) {
          int lc = t2 * 64 + n * 16 + r;
          float bsv = biasc[ntpair[ph][t2] * 64 + n * 16 + r];
#pragma unroll
          for (int q = 0; q < 4; ++q) {
            int row = w * 32 + m * 16 + g * 4 + q;
            As[row * 128 + (lc ^ (((row >> 2) & 3) << 4))] =
                (ushort)f2bf(acc[t2][m][n][q] + bsv);
          }
        }
      }
    }
    __syncthreads();
#pragma unroll
    for (int it = 0; it < 8; ++it) {
      int u = tid + 256 * it;
      int row = u >> 4, mq = u & 15;
      int xo = ((row >> 2) & 3) << 4;
      uint2 lo = *(const uint2*)&As[row * 128 + ((4 * mq) ^ xo)];
      uint2 hi = *(const uint2*)&As[row * 128 + ((64 + 4 * mq) ^ xo)];
      uint4 val = (ph < 2) ? make_uint4(hi.x, lo.x, hi.y, lo.y)
                           : make_uint4(lo.x, hi.x, lo.y, hi.y);
      int gr = m0 + row;
      if (gr < N_NODES)
        *(uint4*)((char*)abde + (size_t)gr * 1024 + (ph * 16 + mq) * 16) = val;
    }
  }
}

// ---------------- K1b: edge-order e_ij kernel — SEQUENTIAL out_e stream ----------------
// Each of 5000 waves owns 64 consecutive edges: indices loaded lane-parallel, then
// 2-edge unrolled gather pipeline; out_e NT-stored in edge order (pure 164MB stream,
// replacing k_node's random-eid scatter writes). Values bit-identical to R17.
__global__ __launch_bounds__(256) void k_edge(
    const int* __restrict__ dst, const int* __restrict__ srcArr,
    const ushort* __restrict__ abde, float* __restrict__ out_e) {
  const int lane = threadIdx.x & 63;
  const int wid = (blockIdx.x << 2) | (threadIdx.x >> 6);  // 5000 waves
  const int base = wid * 64;
  const int dv = dst[base + lane];     // one coalesced load each
  const int sv = srcArr[base + lane];
#pragma unroll 2
  for (int j = 0; j < 64; j += 2) {
    int dA = __shfl(dv, j),     sA = __shfl(sv, j);
    int dB = __shfl(dv, j + 1), sB = __shfl(sv, j + 1);
    uint2 adA = *(const uint2*)((const char*)abde + (size_t)dA * 1024 + 512 + lane * 8);
    uint2 ebA = *(const uint2*)((const char*)abde + (size_t)sA * 1024 + lane * 8);
    uint2 adB = *(const uint2*)((const char*)abde + (size_t)dB * 1024 + 512 + lane * 8);
    uint2 ebB = *(const uint2*)((const char*)abde + (size_t)sB * 1024 + lane * 8);
    float e0 = bf2f(adA.y & 0xffffu) + bf2f(ebA.x & 0xffffu);
    float e1 = bf2f(adA.y >> 16) + bf2f(ebA.x >> 16);
    nt_store2(out_e + (size_t)(base + j) * 128 + 2 * lane, e0, e1);
    float f0 = bf2f(adB.y & 0xffffu) + bf2f(ebB.x & 0xffffu);
    float f1 = bf2f(adB.y >> 16) + bf2f(ebB.x >> 16);
    nt_store2(out_e + (size_t)(base + j + 1) * 128 + 2 * lane, f0, f1);
  }
}

// ---------------- K2b: per-block sums of cnt ----------------
__global__ __launch_bounds__(256) void k_bsum(const int* __restrict__ cnt,
                                              int* __restrict__ bsum2) {
  __shared__ int lds[256];
  int t = threadIdx.x;
  int i = blockIdx.x * 256 + t;
  lds[t] = (i < N_NODES) ? cnt[i] : 0;
  __syncthreads();
#pragma unroll
  for (int off = 128; off > 0; off >>= 1) {
    if (t < off) lds[t] += lds[t + off];
    __syncthreads();
  }
  if (t == 0) bsum2[blockIdx.x] = lds[0];
}

// ---------------- K3: fused scan ----------------
__global__ __launch_bounds__(256) void k_scan(const int* __restrict__ cnt,
                                              const int* __restrict__ bsum2,
                                              int* __restrict__ row_ptr,
                                              int* __restrict__ cursor) {
  __shared__ int ps[256];
  __shared__ int lds[256];
  __shared__ int boff_s;
  const int t = threadIdx.x;
  int a = (2 * t < SCAN_BLOCKS) ? bsum2[2 * t] : 0;
  int b = (2 * t + 1 < SCAN_BLOCKS) ? bsum2[2 * t + 1] : 0;
  ps[t] = a + b;
  __syncthreads();
  for (int off = 1; off < 256; off <<= 1) {
    int v = (t >= off) ? ps[t - off] : 0;
    __syncthreads();
    ps[t] += v;
    __syncthreads();
  }
  if (t == 0) {
    int b0 = blockIdx.x, p = b0 >> 1;
    int pre = (p > 0) ? ps[p - 1] : 0;
    if (b0 & 1) pre += bsum2[b0 - 1];
    boff_s = pre;
  }
  int i = blockIdx.x * 256 + t;
  int v = (i < N_NODES) ? cnt[i] : 0;
  lds[t] = v;
  __syncthreads();  // also publishes boff_s
  for (int off = 1; off < 256; off <<= 1) {
    int u = (t >= off) ? lds[t - off] : 0;
    __syncthreads();
    lds[t] += u;
    __syncthreads();
  }
  if (i < N_NODES) {
    int ex = boff_s + lds[t] - v;
    row_ptr[i] = ex;
    cursor[i] = ex;
  }
  if (blockIdx.x == 0 && t == 0) row_ptr[N_NODES] = N_EDGES;
}

// ---------------- K4: scatter src only (eid no longer needed) ----------------
__global__ __launch_bounds__(256) void k_scatter(const int* __restrict__ dst,
                                                 const int* __restrict__ srcArr,
                                                 int* __restrict__ cursor,
                                                 int* __restrict__ csr_src) {
  int t = blockIdx.x * 256 + threadIdx.x;
  if (t < N_EDGES) {
    int d = dst[t];
    int s = srcArr[t];
    int pos = atomicAdd(&cursor[d], 1);
    csr_src[pos] = s;
  }
}

// ---------------- K5 v7: gather+aggregate only (out_e moved to k_edge) ---------------
__global__ __launch_bounds__(256) void k_node(
    const ushort* __restrict__ abde, const int* __restrict__ row_ptr,
    const int* __restrict__ csr_src,
    ushort* __restrict__ h, float* __restrict__ partials) {
  const int tid = threadIdx.x;
  const int lane = tid & 63;
  const int wid = (blockIdx.x << 2) | (tid >> 6);
  const int nw = NODE_BLOCKS * 4;
  float s0 = 0.f, s1 = 0.f, q0 = 0.f, q1 = 0.f;

  int i = wid;
  int k0 = 0, ke = 0;
  uint2 ad = make_uint2(0u, 0u);
  if (i < N_NODES) {
    k0 = row_ptr[i];
    ke = row_ptr[i + 1];
    ad = *(const uint2*)((const char*)abde + (size_t)i * 1024 + 512 + lane * 8);  // Ax|Dx
  }
  while (i < N_NODES) {
    const int inext = i + nw;
    int nk0 = 0, nke = 0;
    uint2 nad = make_uint2(0u, 0u);
    if (inext < N_NODES) {
      nk0 = row_ptr[inext];
      nke = row_ptr[inext + 1];
      nad = *(const uint2*)((const char*)abde + (size_t)inext * 1024 + 512 + lane * 8);
    }
    float ax0 = bf2f(ad.x & 0xffffu), ax1 = bf2f(ad.x >> 16);
    float dx0 = bf2f(ad.y & 0xffffu), dx1 = bf2f(ad.y >> 16);
    float n0 = 0.f, n1 = 0.f, d0 = 0.f, d1 = 0.f;
    for (int base = k0; base < ke; base += 64) {
      const int cnt = min(64, ke - base);
      int srcv = 0;
      if (lane < cnt) srcv = csr_src[base + lane];  // coalesced
      int j = 0;
      for (; j + 2 <= cnt; j += 2) {
        int sA = __shfl(srcv, j);
        int sB = __shfl(srcv, j + 1);
        uint2 ebA = *(const uint2*)((const char*)abde + (size_t)sA * 1024 + lane * 8);
        uint2 ebB = *(const uint2*)((const char*)abde + (size_t)sB * 1024 + lane * 8);
        float e0 = dx0 + bf2f(ebA.x & 0xffffu);
        float e1 = dx1 + bf2f(ebA.x >> 16);
        float sg0 = 1.f / (1.f + __expf(-e0));
        float sg1 = 1.f / (1.f + __expf(-e1));
        n0 += sg0 * bf2f(ebA.y & 0xffffu); n1 += sg1 * bf2f(ebA.y >> 16);
        d0 += sg0; d1 += sg1;
        float f0 = dx0 + bf2f(ebB.x & 0xffffu);
        float f1 = dx1 + bf2f(ebB.x >> 16);
        float tg0 = 1.f / (1.f + __expf(-f0));
        float tg1 = 1.f / (1.f + __expf(-f1));
        n0 += tg0 * bf2f(ebB.y & 0xffffu); n1 += tg1 * bf2f(ebB.y >> 16);
        d0 += tg0; d1 += tg1;
      }
      if (j < cnt) {
        int sA = __shfl(srcv, j);
        uint2 ebA = *(const uint2*)((const char*)abde + (size_t)sA * 1024 + lane * 8);
        float e0 = dx0 + bf2f(ebA.x & 0xffffu);
        float e1 = dx1 + bf2f(ebA.x >> 16);
        float sg0 = 1.f / (1.f + __expf(-e0));
        float sg1 = 1.f / (1.f + __expf(-e1));
        n0 += sg0 * bf2f(ebA.y & 0xffffu); n1 += sg1 * bf2f(ebA.y >> 16);
        d0 += sg0; d1 += sg1;
      }
    }
    float h0 = ax0 + n0 / (d0 + AGG_EPS);
    float h1 = ax1 + n1 / (d1 + AGG_EPS);
    *(uint32_t*)(h + (size_t)i * 128 + 2 * lane) = f2bf(h0) | (f2bf(h1) << 16);
    s0 += h0; s1 += h1; q0 += h0 * h0; q1 += h1 * h1;
    i = inext; k0 = nk0; ke = nke; ad = nad;
  }
  __shared__ float red[256 * 4];
  red[tid] = s0; red[256 + tid] = s1; red[512 + tid] = q0; red[768 + tid] = q1;
  __syncthreads();
  if (tid < 64) {
    float vs0 = red[tid] + red[tid + 64] + red[tid + 128] + red[tid + 192];
    float vs1 = red[256 + tid] + red[256 + tid + 64] + red[256 + tid + 128] + red[256 + tid + 192];
    float vq0 = red[512 + tid] + red[512 + tid + 64] + red[512 + tid + 128] + red[512 + tid + 192];
    float vq1 = red[768 + tid] + red[768 + tid + 64] + red[768 + tid + 128] + red[768 + tid + 192];
    float* p = partials + blockIdx.x * 256;
    p[2 * tid] = vs0;
    p[2 * tid + 1] = vs1;
    p[128 + 2 * tid] = vq0;
    p[128 + 2 * tid + 1] = vq1;
  }
}

// ---------------- K6: fused stats (64 blocks reduce; last block finalizes) -------------
__global__ __launch_bounds__(256) void k_stats(const float* __restrict__ partials,
                                               float* __restrict__ out2,
                                               float* __restrict__ stats,
                                               int* __restrict__ done) {
  const int t = threadIdx.x, b = blockIdx.x;  // 64 blocks
  float s = 0.f;
#pragma unroll
  for (int j = 0; j < 32; ++j) s += partials[(b * 32 + j) * 256 + t];
  out2[b * 256 + t] = s;
  __threadfence();
  __shared__ int ticket;
  if (t == 0) ticket = atomicAdd(done, 1);
  __syncthreads();
  if (ticket == 63 && t < 128) {
    float ss = 0.f, qq = 0.f;
#pragma unroll
    for (int bb = 0; bb < 64; ++bb) {
      ss += out2[bb * 256 + t];
      qq += out2[bb * 256 + 128 + t];
    }
    float mean = ss * (1.f / (float)N_NODES);
    float var = qq * (1.f / (float)N_NODES) - mean * mean;
    stats[t] = mean;
    stats[128 + t] = rsqrtf(var + BN_EPS);
  }
}

// ---------------- K7: normalize + ReLU (NT stores) ----------------
__global__ __launch_bounds__(256) void k_final(const ushort* __restrict__ h,
    const float* __restrict__ gamma, const float* __restrict__ beta,
    const float* __restrict__ stats, float* __restrict__ out_x) {
  int idx = blockIdx.x * 256 + threadIdx.x;
  int c = (idx & 15) * 8;
  uint4 hv = *(const uint4*)(h + idx * 8);
  uint32_t hw[4] = {hv.x, hv.y, hv.z, hv.w};
  float out[8];
#pragma unroll
  for (int j = 0; j < 8; ++j) {
    uint32_t u = (j & 1) ? (hw[j >> 1] >> 16) : (hw[j >> 1] & 0xffffu);
    float hf = bf2f(u);
    int cc = c + j;
    float v = gamma[cc] * (hf - stats[cc]) * stats[128 + cc] + beta[cc];
    out[j] = fmaxf(v, 0.f);
  }
  f32x4 v0 = {out[0], out[1], out[2], out[3]};
  f32x4 v1 = {out[4], out[5], out[6], out[7]};
  __builtin_nontemporal_store(v0, (f32x4*)(out_x + idx * 8));
  __builtin_nontemporal_store(v1, (f32x4*)(out_x + idx * 8 + 4));
}

extern "C" void kernel_launch(void* const* d_in, const int* in_sizes, int n_in,
                              void* d_out, int out_size, void* d_ws, size_t ws_size,
                              hipStream_t stream) {
  const float* x = (const float*)d_in[0];
  const int* edge_index = (const int*)d_in[2];
  const float* Wa = (const float*)d_in[3];
  const float* ba = (const float*)d_in[4];
  const float* Wb = (const float*)d_in[5];
  const float* bb = (const float*)d_in[6];
  const float* Wd = (const float*)d_in[7];
  const float* bd = (const float*)d_in[8];
  const float* We = (const float*)d_in[9];
  const float* be = (const float*)d_in[10];
  const float* gamma = (const float*)d_in[11];
  const float* beta = (const float*)d_in[12];

  const int* src = edge_index;            // edge_index[0]
  const int* dst = edge_index + N_EDGES;  // edge_index[1]

  // workspace layout (bytes), all 16B-aligned; total ~132.7 MB
  char* w = (char*)d_ws;
  ushort* wt      = (ushort*)(w);               // 131072
  float*  biasc   = (float*)(w + 131072);       // 2048
  ushort* abde    = (ushort*)(w + 133120);      // 102,400,000
  ushort* hbuf    = (ushort*)(w + 102533120);   // 25,600,000
  int*    cnt     = (int*)(w + 128133120);      // 400,000
  int*    row_ptr = (int*)(w + 128533120);      // 400,128 (100,001 ints + slack)
  int*    cursor  = (int*)(w + 128933248);      // 400,000
  int*    csr_src = (int*)(w + 129333248);      // 1,280,000 (was csr_eid)
  float*  partials= (float*)(w + 130613248);    // 2,097,152
  float*  stats   = (float*)(w + 132710400);    // 1024

  // overlays (no ws growth):
  int*   bsum2 = (int*)partials;        // 391 ints; dead before k_node writes partials
  float* out2  = (float*)cnt;           // cnt dead after k_scan; overwritten by k_stats
  int*   done  = row_ptr + 100001;      // 4B slack past row_ptr[N_NODES]

  float* out_x = (float*)d_out;
  float* out_e = out_x + (size_t)N_NODES * DIM;

  k_prep<<<16, 256, 0, stream>>>(Wa, ba, Wb, bb, Wd, bd, We, be, wt, biasc,
                                 (uint4*)cnt, done);
  k_gemm_count<<<GEMM_BLOCKS + EDGE_BLOCKS, 256, 0, stream>>>(x, wt, biasc, abde, dst, cnt);
  k_edge<<<1250, 256, 0, stream>>>(dst, src, abde, out_e);
  k_bsum<<<SCAN_BLOCKS, 256, 0, stream>>>(cnt, bsum2);
  k_scan<<<SCAN_BLOCKS, 256, 0, stream>>>(cnt, bsum2, row_ptr, cursor);
  k_scatter<<<EDGE_BLOCKS, 256, 0, stream>>>(dst, src, cursor, csr_src);
  k_node<<<NODE_BLOCKS, 256, 0, stream>>>(abde, row_ptr, csr_src, hbuf, partials);
  k_stats<<<64, 256, 0, stream>>>(partials, out2, stats, done);
  k_final<<<6250, 256, 0, stream>>>(hbuf, gamma, beta, stats, out_x);
}

// Round 19
// 168.505 us; speedup vs baseline: 1.2786x; 1.2786x over previous
//
#include <hip/hip_runtime.h>
#include <hip/hip_bf16.h>
#include <stdint.h>

#define N_NODES 100000
#define N_EDGES 320000
#define DIM 128
#define AGG_EPS 1e-6f
#define BN_EPS 1e-5f
#define NODE_BLOCKS 2048
#define SCAN_BLOCKS 391   // ceil(100000/256)
#define GEMM_BLOCKS 782   // ceil(100000/128)
#define EDGE_BLOCKS 1250  // ceil(320000/256)

typedef float f32x4 __attribute__((ext_vector_type(4)));
typedef float f32x2 __attribute__((ext_vector_type(2)));
typedef __bf16 bf16x8 __attribute__((ext_vector_type(8)));

__device__ __forceinline__ uint32_t f2bf(float f) {
  union { float f; uint32_t u; } v; v.f = f;
  uint32_t u = v.u;
  return (u + 0x7fffu + ((u >> 16) & 1u)) >> 16;  // RNE
}
__device__ __forceinline__ float bf2f(uint32_t h) {
  union { uint32_t u; float f; } v; v.u = h << 16;
  return v.f;
}
__device__ __forceinline__ void nt_store2(float* p, float a, float b) {
  f32x2 v = {a, b};
  __builtin_nontemporal_store(v, (f32x2*)p);
}

// abde row layout (1024 B per node):
//   [0,512):   interleaved Ex|Bx  (lane l uint2 -> ex pair, bx pair)
//   [512,1024): interleaved Ax|Dx

// ---------------- K0: W -> wt transposed bf16; bias; zero cnt + done ----------
__global__ __launch_bounds__(256) void k_prep(
    const float* __restrict__ Wa, const float* __restrict__ ba,
    const float* __restrict__ Wb, const float* __restrict__ bb,
    const float* __restrict__ Wd, const float* __restrict__ bd,
    const float* __restrict__ We, const float* __restrict__ be,
    ushort* __restrict__ wt, float* __restrict__ biasc,
    uint4* __restrict__ cnt_zero, int* __restrict__ done) {
  __shared__ float tile[64][65];
  const int tid = threadIdx.x;
  const int b = blockIdx.x;
  const int sel = b >> 2, tr = (b >> 1) & 1, tc = b & 1;
  const float* W = (sel == 0) ? Wa : (sel == 1) ? Wb : (sel == 2) ? Wd : We;
#pragma unroll
  for (int i = 0; i < 16; ++i) {
    int idx = tid + 256 * i;
    int lr = idx >> 6, lc = idx & 63;
    tile[lr][lc] = W[(tr * 64 + lr) * 128 + tc * 64 + lc];
  }
  __syncthreads();
#pragma unroll
  for (int i = 0; i < 16; ++i) {
    int idx = tid + 256 * i;
    int oc = idx >> 6, ok = idx & 63;
    wt[(sel * 128 + tc * 64 + oc) * 128 + tr * 64 + ok] = (ushort)f2bf(tile[ok][oc]);
  }
  if (b == 0) {
    for (int t = tid; t < 512; t += 256) {
      int s2 = t >> 7;
      const float* bp = (s2 == 0) ? ba : (s2 == 1) ? bb : (s2 == 2) ? bd : be;
      biasc[t] = bp[t & 127];
    }
    if (tid == 0) *done = 0;
  }
  for (int j = b * 256 + tid; j < 25000; j += 16 * 256)
    cnt_zero[j] = make_uint4(0u, 0u, 0u, 0u);
}

// ---------------- K1: mixed-role — blocks <GEMM_BLOCKS: ABDE gemm; rest: edge count ----
__global__ __launch_bounds__(256) void k_gemm_count(
    const float* __restrict__ x, const ushort* __restrict__ wt,
    const float* __restrict__ biasc, ushort* __restrict__ abde,
    const int* __restrict__ dst, int* __restrict__ cnt) {
  __shared__ ushort As[128 * 128];  // 32KB: A tile; reused as bounce buffer
  __shared__ ushort Bs[64 * 128];   // 16KB
  const int tid = threadIdx.x;
  const int bid = blockIdx.x;

  if (bid >= GEMM_BLOCKS) {  // ---- count role ----
    int e = (bid - GEMM_BLOCKS) * 256 + tid;
    if (e < N_EDGES) atomicAdd(&cnt[dst[e]], 1);
    return;
  }
  const int m0 = bid * 128;

#pragma unroll
  for (int i = 0; i < 8; ++i) {
    int qid = tid + 256 * i;
    int row = qid >> 4, q = qid & 15;
    int gr = m0 + row;
    uint4 pk = make_uint4(0u, 0u, 0u, 0u);
    if (gr < N_NODES) {
      const float* s = x + (size_t)gr * 128 + q * 8;
      float4 f0 = *(const float4*)(s);
      float4 f1 = *(const float4*)(s + 4);
      pk.x = f2bf(f0.x) | (f2bf(f0.y) << 16);
      pk.y = f2bf(f0.z) | (f2bf(f0.w) << 16);
      pk.z = f2bf(f1.x) | (f2bf(f1.y) << 16);
      pk.w = f2bf(f1.z) | (f2bf(f1.w) << 16);
    }
    int byte = (row * 256 + q * 16) ^ ((row & 7) << 4);
    *(uint4*)((char*)As + byte) = pk;
  }
  __syncthreads();

  const int w = tid >> 6, lane = tid & 63;
  const int r = lane & 15, g = lane >> 4;

  bf16x8 afrag[2][4];
#pragma unroll
  for (int m = 0; m < 2; ++m)
#pragma unroll
    for (int kk = 0; kk < 4; ++kk) {
      int arow = w * 32 + m * 16 + r;
      int ab = (arow * 256 + kk * 64 + g * 16) ^ ((arow & 7) << 4);
      afrag[m][kk] = *(const bf16x8*)((const char*)As + ab);
    }

  const int ntpair[4][2] = {{2, 6}, {3, 7}, {0, 4}, {1, 5}};
  for (int ph = 0; ph < 4; ++ph) {
    f32x4 acc[2][2][4] = {};  // [t2][m][n]
#pragma unroll
    for (int t2 = 0; t2 < 2; ++t2) {
      if (ph | t2) __syncthreads();
      const int n0 = ntpair[ph][t2] * 64;
#pragma unroll
      for (int i = 0; i < 4; ++i) {
        int qid = tid + 256 * i;
        int row = qid >> 4, q = qid & 15;
        uint4 v = *(const uint4*)(wt + (n0 + row) * 128 + q * 8);
        int byte = (row * 256 + q * 16) ^ ((row & 7) << 4);
        *(uint4*)((char*)Bs + byte) = v;
      }
      __syncthreads();
#pragma unroll
      for (int kk = 0; kk < 4; ++kk) {
        bf16x8 bv[4];
#pragma unroll
        for (int n = 0; n < 4; ++n) {
          int brow = n * 16 + r;
          int bb = (brow * 256 + kk * 64 + g * 16) ^ ((brow & 7) << 4);
          bv[n] = *(const bf16x8*)((const char*)Bs + bb);
        }
#pragma unroll
        for (int m = 0; m < 2; ++m)
#pragma unroll
          for (int n = 0; n < 4; ++n)
            acc[t2][m][n] = __builtin_amdgcn_mfma_f32_16x16x32_bf16(
                afrag[m][kk], bv[n], acc[t2][m][n], 0, 0, 0);
      }
    }
#pragma unroll
    for (int t2 = 0; t2 < 2; ++t2) {
#pragma unroll
      for (int m = 0; m < 2; ++m) {
#pragma unroll
        for (int n = 0; n < 4; ++n) {
          int lc = t2 * 64 + n * 16 + r;
          float bsv = biasc[ntpair[ph][t2] * 64 + n * 16 + r];
#pragma unroll
          for (int q = 0; q < 4; ++q) {
            int row = w * 32 + m * 16 + g * 4 + q;
            As[row * 128 + (lc ^ (((row >> 2) & 3) << 4))] =
                (ushort)f2bf(acc[t2][m][n][q] + bsv);
          }
        }
      }
    }
    __syncthreads();
#pragma unroll
    for (int it = 0; it < 8; ++it) {
      int u = tid + 256 * it;
      int row = u >> 4, mq = u & 15;
      int xo = ((row >> 2) & 3) << 4;
      uint2 lo = *(const uint2*)&As[row * 128 + ((4 * mq) ^ xo)];
      uint2 hi = *(const uint2*)&As[row * 128 + ((64 + 4 * mq) ^ xo)];
      uint4 val = (ph < 2) ? make_uint4(hi.x, lo.x, hi.y, lo.y)
                           : make_uint4(lo.x, hi.x, lo.y, hi.y);
      int gr = m0 + row;
      if (gr < N_NODES)
        *(uint4*)((char*)abde + (size_t)gr * 1024 + (ph * 16 + mq) * 16) = val;
    }
  }
}

// ---------------- K2b: per-block sums of cnt ----------------
__global__ __launch_bounds__(256) void k_bsum(const int* __restrict__ cnt,
                                              int* __restrict__ bsum2) {
  __shared__ int lds[256];
  int t = threadIdx.x;
  int i = blockIdx.x * 256 + t;
  lds[t] = (i < N_NODES) ? cnt[i] : 0;
  __syncthreads();
#pragma unroll
  for (int off = 128; off > 0; off >>= 1) {
    if (t < off) lds[t] += lds[t + off];
    __syncthreads();
  }
  if (t == 0) bsum2[blockIdx.x] = lds[0];
}

// ---------------- K3: fused scan ----------------
__global__ __launch_bounds__(256) void k_scan(const int* __restrict__ cnt,
                                              const int* __restrict__ bsum2,
                                              int* __restrict__ row_ptr,
                                              int* __restrict__ cursor) {
  __shared__ int ps[256];
  __shared__ int lds[256];
  __shared__ int boff_s;
  const int t = threadIdx.x;
  int a = (2 * t < SCAN_BLOCKS) ? bsum2[2 * t] : 0;
  int b = (2 * t + 1 < SCAN_BLOCKS) ? bsum2[2 * t + 1] : 0;
  ps[t] = a + b;
  __syncthreads();
  for (int off = 1; off < 256; off <<= 1) {
    int v = (t >= off) ? ps[t - off] : 0;
    __syncthreads();
    ps[t] += v;
    __syncthreads();
  }
  if (t == 0) {
    int b0 = blockIdx.x, p = b0 >> 1;
    int pre = (p > 0) ? ps[p - 1] : 0;
    if (b0 & 1) pre += bsum2[b0 - 1];
    boff_s = pre;
  }
  int i = blockIdx.x * 256 + t;
  int v = (i < N_NODES) ? cnt[i] : 0;
  lds[t] = v;
  __syncthreads();  // also publishes boff_s
  for (int off = 1; off < 256; off <<= 1) {
    int u = (t >= off) ? lds[t - off] : 0;
    __syncthreads();
    lds[t] += u;
    __syncthreads();
  }
  if (i < N_NODES) {
    int ex = boff_s + lds[t] - v;
    row_ptr[i] = ex;
    cursor[i] = ex;
  }
  if (blockIdx.x == 0 && t == 0) row_ptr[N_NODES] = N_EDGES;
}

// ---------------- K4: scatter eid AND src ----------------
__global__ __launch_bounds__(256) void k_scatter(const int* __restrict__ dst,
                                                 const int* __restrict__ srcArr,
                                                 int* __restrict__ cursor,
                                                 int* __restrict__ csr_eid,
                                                 int* __restrict__ csr_src) {
  int t = blockIdx.x * 256 + threadIdx.x;
  if (t < N_EDGES) {
    int d = dst[t];
    int s = srcArr[t];
    int pos = atomicAdd(&cursor[d], 1);
    csr_eid[pos] = t;
    csr_src[pos] = s;
  }
}

// ---------------- K5: wave-per-node fused edge+aggregate+h+BN-partials (NT out_e) ------
__global__ __launch_bounds__(256) void k_node(
    const ushort* __restrict__ abde, const int* __restrict__ row_ptr,
    const int* __restrict__ csr_eid, const int* __restrict__ csr_src,
    float* __restrict__ out_e, ushort* __restrict__ h,
    float* __restrict__ partials) {
  const int tid = threadIdx.x;
  const int lane = tid & 63;
  const int wid = (blockIdx.x << 2) | (tid >> 6);
  const int nw = NODE_BLOCKS * 4;
  float s0 = 0.f, s1 = 0.f, q0 = 0.f, q1 = 0.f;

  int i = wid;
  int k0 = 0, ke = 0;
  uint2 ad = make_uint2(0u, 0u);
  if (i < N_NODES) {
    k0 = row_ptr[i];
    ke = row_ptr[i + 1];
    ad = *(const uint2*)((const char*)abde + (size_t)i * 1024 + 512 + lane * 8);  // Ax|Dx
  }
  while (i < N_NODES) {
    const int inext = i + nw;
    int nk0 = 0, nke = 0;
    uint2 nad = make_uint2(0u, 0u);
    if (inext < N_NODES) {
      nk0 = row_ptr[inext];
      nke = row_ptr[inext + 1];
      nad = *(const uint2*)((const char*)abde + (size_t)inext * 1024 + 512 + lane * 8);
    }
    float ax0 = bf2f(ad.x & 0xffffu), ax1 = bf2f(ad.x >> 16);
    float dx0 = bf2f(ad.y & 0xffffu), dx1 = bf2f(ad.y >> 16);
    float n0 = 0.f, n1 = 0.f, d0 = 0.f, d1 = 0.f;
    for (int base = k0; base < ke; base += 64) {
      const int cnt = min(64, ke - base);
      int eidv = 0, srcv = 0;
      if (lane < cnt) {
        eidv = csr_eid[base + lane];
        srcv = csr_src[base + lane];
      }
      int j = 0;
      for (; j + 2 <= cnt; j += 2) {
        int eA = __shfl(eidv, j),     sA = __shfl(srcv, j);
        int eB = __shfl(eidv, j + 1), sB = __shfl(srcv, j + 1);
        uint2 ebA = *(const uint2*)((const char*)abde + (size_t)sA * 1024 + lane * 8);
        uint2 ebB = *(const uint2*)((const char*)abde + (size_t)sB * 1024 + lane * 8);
        float e0 = dx0 + bf2f(ebA.x & 0xffffu);
        float e1 = dx1 + bf2f(ebA.x >> 16);
        nt_store2(out_e + (size_t)eA * 128 + 2 * lane, e0, e1);
        float sg0 = 1.f / (1.f + __expf(-e0));
        float sg1 = 1.f / (1.f + __expf(-e1));
        n0 += sg0 * bf2f(ebA.y & 0xffffu); n1 += sg1 * bf2f(ebA.y >> 16);
        d0 += sg0; d1 += sg1;
        float f0 = dx0 + bf2f(ebB.x & 0xffffu);
        float f1 = dx1 + bf2f(ebB.x >> 16);
        nt_store2(out_e + (size_t)eB * 128 + 2 * lane, f0, f1);
        float tg0 = 1.f / (1.f + __expf(-f0));
        float tg1 = 1.f / (1.f + __expf(-f1));
        n0 += tg0 * bf2f(ebB.y & 0xffffu); n1 += tg1 * bf2f(ebB.y >> 16);
        d0 += tg0; d1 += tg1;
      }
      if (j < cnt) {
        int eA = __shfl(eidv, j), sA = __shfl(srcv, j);
        uint2 ebA = *(const uint2*)((const char*)abde + (size_t)sA * 1024 + lane * 8);
        float e0 = dx0 + bf2f(ebA.x & 0xffffu);
        float e1 = dx1 + bf2f(ebA.x >> 16);
        nt_store2(out_e + (size_t)eA * 128 + 2 * lane, e0, e1);
        float sg0 = 1.f / (1.f + __expf(-e0));
        float sg1 = 1.f / (1.f + __expf(-e1));
        n0 += sg0 * bf2f(ebA.y & 0xffffu); n1 += sg1 * bf2f(ebA.y >> 16);
        d0 += sg0; d1 += sg1;
      }
    }
    float h0 = ax0 + n0 / (d0 + AGG_EPS);
    float h1 = ax1 + n1 / (d1 + AGG_EPS);
    *(uint32_t*)(h + (size_t)i * 128 + 2 * lane) = f2bf(h0) | (f2bf(h1) << 16);
    s0 += h0; s1 += h1; q0 += h0 * h0; q1 += h1 * h1;
    i = inext; k0 = nk0; ke = nke; ad = nad;
  }
  __shared__ float red[256 * 4];
  red[tid] = s0; red[256 + tid] = s1; red[512 + tid] = q0; red[768 + tid] = q1;
  __syncthreads();
  if (tid < 64) {
    float vs0 = red[tid] + red[tid + 64] + red[tid + 128] + red[tid + 192];
    float vs1 = red[256 + tid] + red[256 + tid + 64] + red[256 + tid + 128] + red[256 + tid + 192];
    float vq0 = red[512 + tid] + red[512 + tid + 64] + red[512 + tid + 128] + red[512 + tid + 192];
    float vq1 = red[768 + tid] + red[768 + tid + 64] + red[768 + tid + 128] + red[768 + tid + 192];
    float* p = partials + blockIdx.x * 256;
    p[2 * tid] = vs0;
    p[2 * tid + 1] = vs1;
    p[128 + 2 * tid] = vq0;
    p[128 + 2 * tid + 1] = vq1;
  }
}

// ---------------- K6: fused stats (64 blocks reduce; last block finalizes) -------------
__global__ __launch_bounds__(256) void k_stats(const float* __restrict__ partials,
                                               float* __restrict__ out2,
                                               float* __restrict__ stats,
                                               int* __restrict__ done) {
  const int t = threadIdx.x, b = blockIdx.x;  // 64 blocks
  float s = 0.f;
#pragma unroll
  for (int j = 0; j < 32; ++j) s += partials[(b * 32 + j) * 256 + t];
  out2[b * 256 + t] = s;
  __threadfence();
  __shared__ int ticket;
  if (t == 0) ticket = atomicAdd(done, 1);
  __syncthreads();
  if (ticket == 63 && t < 128) {  // deterministic: same full out2, same order
    float ss = 0.f, qq = 0.f;
#pragma unroll
    for (int bb = 0; bb < 64; ++bb) {
      ss += out2[bb * 256 + t];
      qq += out2[bb * 256 + 128 + t];
    }
    float mean = ss * (1.f / (float)N_NODES);
    float var = qq * (1.f / (float)N_NODES) - mean * mean;
    stats[t] = mean;
    stats[128 + t] = rsqrtf(var + BN_EPS);
  }
}

// ---------------- K7: normalize + ReLU (NT stores) ----------------
__global__ __launch_bounds__(256) void k_final(const ushort* __restrict__ h,
    const float* __restrict__ gamma, const float* __restrict__ beta,
    const float* __restrict__ stats, float* __restrict__ out_x) {
  int idx = blockIdx.x * 256 + threadIdx.x;
  int c = (idx & 15) * 8;
  uint4 hv = *(const uint4*)(h + idx * 8);
  uint32_t hw[4] = {hv.x, hv.y, hv.z, hv.w};
  float out[8];
#pragma unroll
  for (int j = 0; j < 8; ++j) {
    uint32_t u = (j & 1) ? (hw[j >> 1] >> 16) : (hw[j >> 1] & 0xffffu);
    float hf = bf2f(u);
    int cc = c + j;
    float v = gamma[cc] * (hf - stats[cc]) * stats[128 + cc] + beta[cc];
    out[j] = fmaxf(v, 0.f);
  }
  f32x4 v0 = {out[0], out[1], out[2], out[3]};
  f32x4 v1 = {out[4], out[5], out[6], out[7]};
  __builtin_nontemporal_store(v0, (f32x4*)(out_x + idx * 8));
  __builtin_nontemporal_store(v1, (f32x4*)(out_x + idx * 8 + 4));
}

extern "C" void kernel_launch(void* const* d_in, const int* in_sizes, int n_in,
                              void* d_out, int out_size, void* d_ws, size_t ws_size,
                              hipStream_t stream) {
  const float* x = (const float*)d_in[0];
  const int* edge_index = (const int*)d_in[2];
  const float* Wa = (const float*)d_in[3];
  const float* ba = (const float*)d_in[4];
  const float* Wb = (const float*)d_in[5];
  const float* bb = (const float*)d_in[6];
  const float* Wd = (const float*)d_in[7];
  const float* bd = (const float*)d_in[8];
  const float* We = (const float*)d_in[9];
  const float* be = (const float*)d_in[10];
  const float* gamma = (const float*)d_in[11];
  const float* beta = (const float*)d_in[12];

  const int* src = edge_index;            // edge_index[0]
  const int* dst = edge_index + N_EDGES;  // edge_index[1]

  // workspace layout (bytes), all 16B-aligned; total ~132.7 MB
  char* w = (char*)d_ws;
  ushort* wt      = (ushort*)(w);               // 131072
  float*  biasc   = (float*)(w + 131072);       // 2048
  ushort* abde    = (ushort*)(w + 133120);      // 102,400,000
  ushort* hbuf    = (ushort*)(w + 102533120);   // 25,600,000
  int*    cnt     = (int*)(w + 128133120);      // 400,000
  int*    row_ptr = (int*)(w + 128533120);      // 400,128 (100,001 ints + slack)
  int*    cursor  = (int*)(w + 128933248);      // 400,000
  int*    csr_eid = (int*)(w + 129333248);      // 1,280,000
  float*  partials= (float*)(w + 130613248);    // 2,097,152
  float*  stats   = (float*)(w + 132710400);    // 1024

  // overlays (no ws growth):
  int*   bsum2 = (int*)partials;        // 391 ints; dead before k_node writes partials
  float* out2  = (float*)cnt;           // cnt dead after k_scan; overwritten by k_stats
  int*   done  = row_ptr + 100001;      // 4B slack past row_ptr[N_NODES]

  float* out_x = (float*)d_out;
  float* out_e = out_x + (size_t)N_NODES * DIM;
  int* csr_src = (int*)out_x;  // scratch in d_out; dead before k_final overwrites

  k_prep<<<16, 256, 0, stream>>>(Wa, ba, Wb, bb, Wd, bd, We, be, wt, biasc,
                                 (uint4*)cnt, done);
  k_gemm_count<<<GEMM_BLOCKS + EDGE_BLOCKS, 256, 0, stream>>>(x, wt, biasc, abde, dst, cnt);
  k_bsum<<<SCAN_BLOCKS, 256, 0, stream>>>(cnt, bsum2);
  k_scan<<<SCAN_BLOCKS, 256, 0, stream>>>(cnt, bsum2, row_ptr, cursor);
  k_scatter<<<EDGE_BLOCKS, 256, 0, stream>>>(dst, src, cursor, csr_eid, csr_src);
  k_node<<<NODE_BLOCKS, 256, 0, stream>>>(abde, row_ptr, csr_eid, csr_src, out_e, hbuf, partials);
  k_stats<<<64, 256, 0, stream>>>(partials, out2, stats, done);
  k_final<<<6250, 256, 0, stream>>>(hbuf, gamma, beta, stats, out_x);
}